// Round 9
// baseline (332.988 us; speedup 1.0000x reference)
//
#include <hip/hip_runtime.h>
#include <hip/hip_bf16.h>
#include <stdint.h>

typedef __bf16 bf16x8 __attribute__((ext_vector_type(8)));
typedef float floatx4 __attribute__((ext_vector_type(4)));

// ---------------------------------------------------------------------------
// Async global->LDS 16B copy (wave-uniform LDS base + lane*16; per-lane
// global address OK).
// ---------------------------------------------------------------------------
__device__ __forceinline__ void async_copy16(void* lds, const void* g) {
    __builtin_amdgcn_global_load_lds(
        (const __attribute__((address_space(1))) unsigned int*)g,
        (__attribute__((address_space(3))) unsigned int*)lds,
        16, 0, 0);
}

// ---------------------------------------------------------------------------
// Fused prep, one dispatch (UNCHANGED):
//   blocks [0, nConv)         : x fp32 -> bf16 (8 elems/thread, float4 loads)
//   blocks [nConv, nConv+1280): Wrot[o,d] = sum_k kron(K1,K2,K3)[d,k] W[o,k]
// ---------------------------------------------------------------------------
__global__ __launch_bounds__(256)
void prep(const float* __restrict__ x,
          const float* __restrict__ W,
          const float* __restrict__ K1,
          const float* __restrict__ K2,
          const float* __restrict__ K3,
          __hip_bfloat16* __restrict__ x_bf,
          __hip_bfloat16* __restrict__ Wrot,
          int nConv) {
    const int tid = threadIdx.x;

    if ((int)blockIdx.x < nConv) {
        const size_t i = ((size_t)blockIdx.x * 256 + tid) * 8;
        const float4 a = *(const float4*)(x + i);
        const float4 b = *(const float4*)(x + i + 4);
        bf16x8 v;
        v[0] = (__bf16)a.x; v[1] = (__bf16)a.y; v[2] = (__bf16)a.z; v[3] = (__bf16)a.w;
        v[4] = (__bf16)b.x; v[5] = (__bf16)b.y; v[6] = (__bf16)b.z; v[7] = (__bf16)b.w;
        *(bf16x8*)((__bf16*)x_bf + i) = v;
        return;
    }

    const int o = blockIdx.x - nConv;
    __shared__ __align__(16) float w0[1280];   // W row, then stage-2 result
    __shared__ __align__(16) float t1[1280];
    __shared__ __align__(16) float k3s[1600];
    __shared__ float k2s[64];
    __shared__ float k1s[16];

    for (int i = tid; i < 1280; i += 256) w0[i] = W[o * 1280 + i];
    for (int i = tid; i < 1600; i += 256) k3s[i] = K3[i];
    if (tid < 64) k2s[tid] = K2[tid];
    if (tid < 16) k1s[tid] = K1[tid];
    __syncthreads();

    for (int i = tid; i < 1280; i += 256) {
        const int p = i / 40, d3 = i % 40;
        const float4* w4 = (const float4*)(w0 + p * 40);
        const float4* k4 = (const float4*)(k3s + d3 * 40);
        float acc = 0.f;
#pragma unroll
        for (int t = 0; t < 10; ++t) {
            const float4 a = w4[t], b = k4[t];
            acc += a.x * b.x + a.y * b.y + a.z * b.z + a.w * b.w;
        }
        t1[i] = acc;
    }
    __syncthreads();

    for (int i = tid; i < 1280; i += 256) {
        const int d3 = i % 40, pd = i / 40;
        const int k1 = pd >> 3, d2 = pd & 7;
        float acc = 0.f;
#pragma unroll
        for (int k2 = 0; k2 < 8; ++k2) acc += t1[(k1 * 8 + k2) * 40 + d3] * k2s[d2 * 8 + k2];
        w0[i] = acc;
    }
    __syncthreads();

    for (int i = tid; i < 1280; i += 256) {
        const int d3 = i % 40, pd = i / 40;
        const int d1 = pd >> 3, d2 = pd & 7;
        float acc = 0.f;
#pragma unroll
        for (int k1 = 0; k1 < 4; ++k1) acc += w0[(k1 * 8 + d2) * 40 + d3] * k1s[d1 * 4 + k1];
        Wrot[(size_t)o * 1280 + i] = __float2bfloat16(acc);
    }
}

// ---------------------------------------------------------------------------
// Main GEMM r15: C[m,n] = sum_k A[m,k] * B[n,k]  (bf16 in, fp32 out/acc)
//
// r14 (A in registers via direct global->VGPR fragment loads, B in LDS)
// with the PROLOGUE VMCNT BUG FIXED:
//   r14 waited vmcnt(4) in the prologue assuming issue order
//   [Bstage x5, afA x4]; the scheduler may interleave the plain afA loads
//   with the async_copy16s, so vmcnt(4) could leave up to 4 Bstage chunks
//   in flight while we ds_read Bs[0] after the barrier -> garbage bf0
//   (measured absmax 1e37).  Prologue now drains vmcnt(0) — runs once,
//   zero steady-state cost.
//   The STEADY-STATE boundary vmcnt(4) is order-robust: outstanding there
//   is at most [afB x4, Bstage x5, afA' x4] in any intra-block order;
//   vmcnt(4) retires >= 9 oldest, and Bstage is always within the oldest 9
//   (afA' issues in ph1, after ph0's sched_barrier).  SAFE.
//
// Structure (unchanged from r14):
//   - A-fragment per lane is 16B contiguous: A[tileM+wm*64+i*16+r16]
//     [t*64 + s*32 + q*8 ..+8] — loaded straight to VGPR, no LDS, no
//     ds_read for A.  Wave footprint 16 rows x 64B contiguous, A is
//     L2/L3-resident (FETCH 33 MB all session).
//   - B: XOR-swizzled dbuf LDS (80 KiB), 5 async_copy16 chunks/tile.
//   - Waves 4M x 2N, wave tile 64x160, acc[4][10] (160 AGPR).
//   - 2 phases + 1 barrier per tile; counted vmcnt(4) at boundary only.
//   - j-outer MFMA clusters: bf[j] ds_reads pipeline under the cluster.
//   - Numerics: per-acc-element k-order (t asc, s0, s1) identical to r9
//     -> bitwise-identical output.
// ---------------------------------------------------------------------------
#define BM 256
#define BN 320
#define BK 64
#define BGRAN 2560   // BN*8 granules (16B each) per buffer = 40 KiB

__global__ __launch_bounds__(512, 1)
void gemm_bt(const __hip_bfloat16* __restrict__ A,   // [M,K] bf16
             const __hip_bfloat16* __restrict__ B,   // [N,K] bf16
             float* __restrict__ C,                  // [M,N] fp32
             int M, int N, int K) {
    __shared__ bf16x8 Bs[2][BGRAN];   // 80 KiB total

    const int tid  = threadIdx.x;
    const int wave = tid >> 6;
    const int lane = tid & 63;
    const int q    = lane >> 4;
    const int r16  = lane & 15;
    const int wm   = wave >> 1;       // 0..3  (4 M-groups)
    const int wn   = wave & 1;        // 0..1  (2 N-groups)

    // XCD-partitioned tile assignment (grid = 64*4 = 256, 8 | 256)
    const int nTilesN = N / BN;               // 4
    const int chunkM  = (M / BM) >> 3;        // 8 M-tiles per XCD
    const int xcd = blockIdx.x & 7;
    const int s   = blockIdx.x >> 3;          // 0..31 within XCD
    const int bm  = xcd * chunkM + s / nTilesN;
    const int bn  = s % nTilesN;
    const int tileM = bm * BM, tileN = bn * BN;

    // B chunk byte offsets (XOR k-granule swizzle folded into SOURCE addr).
    uint32_t boff[5];
#pragma unroll
    for (int c = 0; c < 5; ++c) {
        const int g = c * 512 + tid;
        const int m = g >> 3, kv = (g & 7) ^ (m & 7);
        boff[c] = (uint32_t)(((tileN + m) * K + kv * 8) * 2);
    }
    const char* Bbase = (const char*)B;

    // B LDS fragment granule indices, k-slice 0; slice 1 = idx ^ 4.
    int bi[10];
#pragma unroll
    for (int j = 0; j < 10; ++j) {
        const int n = wn * 160 + j * 16 + r16;
        bi[j] = n * 8 + (q ^ (n & 7));
    }

    // A fragment pointers: lane's element base for row i (k = q*8 + ...).
    const __hip_bfloat16* aptr[4];
#pragma unroll
    for (int i = 0; i < 4; ++i) {
        const int row = tileM + wm * 64 + i * 16 + r16;
        aptr[i] = A + (size_t)row * K + q * 8;
    }

    floatx4 acc[4][10];
#pragma unroll
    for (int i = 0; i < 4; ++i)
#pragma unroll
        for (int j = 0; j < 10; ++j) acc[i][j] = (floatx4){0.f, 0.f, 0.f, 0.f};

    const int nk = K / BK;                    // 20

    // Prologue: Bstage(0) x5 + afA(0) x4; FULL drain (order-robust, 1x cost).
#pragma unroll
    for (int c = 0; c < 5; ++c)
        async_copy16(&Bs[0][c * 512 + wave * 64], Bbase + boff[c]);

    bf16x8 afA[4], afB[4], bf0[10], bf1[10];
#pragma unroll
    for (int i = 0; i < 4; ++i) afA[i] = *(const bf16x8*)(aptr[i]);   // t0,s0

    asm volatile("s_waitcnt vmcnt(0)" ::: "memory");   // r14 bug: was vmcnt(4)
    __builtin_amdgcn_s_barrier();
#pragma unroll
    for (int j = 0; j < 10; ++j) bf0[j] = Bs[0][bi[j]];

    for (int t = 0; t < nk; ++t) {
        const int cur = t & 1, nxt = cur ^ 1;
        const uint32_t kb = (uint32_t)((t + 1) * BK * 2);
        const bool hn = (t + 1 < nk);

        // ---- ph0: issue afB (this tile, s1) + Bstage(t+1) | M(afA x bf0) --
#pragma unroll
        for (int i = 0; i < 4; ++i)
            afB[i] = *(const bf16x8*)(aptr[i] + t * BK + 32);
        if (hn) {
#pragma unroll
            for (int c = 0; c < 5; ++c)
                async_copy16(&Bs[nxt][c * 512 + wave * 64], Bbase + boff[c] + kb);
        }
        __builtin_amdgcn_sched_barrier(0);
        __builtin_amdgcn_s_setprio(1);
#pragma unroll
        for (int j = 0; j < 10; ++j)
#pragma unroll
            for (int i = 0; i < 4; ++i)
                acc[i][j] = __builtin_amdgcn_mfma_f32_16x16x32_bf16(
                    afA[i], bf0[j], acc[i][j], 0, 0, 0);
        __builtin_amdgcn_s_setprio(0);
        __builtin_amdgcn_sched_barrier(0);

        // ---- ph1: issue afA(t+1,s0) | read bf1 (s1) | M(afB x bf1) ----
        if (hn) {
#pragma unroll
            for (int i = 0; i < 4; ++i)
                afA[i] = *(const bf16x8*)(aptr[i] + (t + 1) * BK);
        }
#pragma unroll
        for (int j = 0; j < 10; ++j) bf1[j] = Bs[cur][bi[j] ^ 4];
        __builtin_amdgcn_sched_barrier(0);
        __builtin_amdgcn_s_setprio(1);
#pragma unroll
        for (int j = 0; j < 10; ++j)
#pragma unroll
            for (int i = 0; i < 4; ++i)
                acc[i][j] = __builtin_amdgcn_mfma_f32_16x16x32_bf16(
                    afB[i], bf1[j], acc[i][j], 0, 0, 0);
        __builtin_amdgcn_s_setprio(0);
        __builtin_amdgcn_sched_barrier(0);

        // ---- boundary: Bstage(t+1) landed; read bf0(t+1) ----
        if (hn) {
            asm volatile("s_waitcnt vmcnt(4)" ::: "memory");  // retire Bstage; afA' in flight
            __builtin_amdgcn_sched_barrier(0);
            __builtin_amdgcn_s_barrier();
            __builtin_amdgcn_sched_barrier(0);
#pragma unroll
            for (int j = 0; j < 10; ++j) bf0[j] = Bs[nxt][bi[j]];
            __builtin_amdgcn_sched_barrier(0);
        }
    }

    // epilogue: C/D layout col=lane&15, row=quad*4+reg (m89/m91)
#pragma unroll
    for (int i = 0; i < 4; ++i) {
#pragma unroll
        for (int j = 0; j < 10; ++j) {
            const int col = tileN + wn * 160 + j * 16 + r16;
#pragma unroll
            for (int r = 0; r < 4; ++r) {
                const int row = tileM + wm * 64 + i * 16 + q * 4 + r;
                C[(size_t)row * N + col] = acc[i][j][r];
            }
        }
    }
}

// ---------------------------------------------------------------------------
extern "C" void kernel_launch(void* const* d_in, const int* in_sizes, int n_in,
                              void* d_out, int out_size, void* d_ws, size_t ws_size,
                              hipStream_t stream) {
    const float* x  = (const float*)d_in[0];  // [4,4096,1280] fp32
    const float* W  = (const float*)d_in[1];  // [1280,1280]  fp32
    const float* K1 = (const float*)d_in[2];  // [4,4]
    const float* K2 = (const float*)d_in[3];  // [8,8]
    const float* K3 = (const float*)d_in[4];  // [40,40]
    float* out = (float*)d_out;               // [4,4096,1280] fp32

    const int D = 1280;
    const int M = in_sizes[0] / D;            // 16384
    const int N = D, K = D;

    // ws layout: [0, M*K) bf16 x ; then [+, N*K) bf16 Wrot
    __hip_bfloat16* x_bf = (__hip_bfloat16*)d_ws;
    __hip_bfloat16* Wrot = x_bf + (size_t)M * K;

    const int nConv = (M * K) / (256 * 8);    // 10240
    prep<<<nConv + D, 256, 0, stream>>>(x, W, K1, K2, K3, x_bf, Wrot, nConv);
    gemm_bt<<<(M / BM) * (N / BN), 512, 0, stream>>>(x_bf, Wrot, out, M, N, K);
}